// Round 15
// baseline (276.414 us; speedup 1.0000x reference)
//
#include <hip/hip_runtime.h>
#include <stdint.h>

#define H    128
#define NBAT 128
#define AD   256
#define NP   65536
#define NL   32768
#define NTOT2 (3 * NP)              // intra | inter | map concatenated CSR nodes
#define NB   384                    // coarse buckets (dst >> 9)
#define BKT  512                    // nodes per bucket
#define EPB  4096                   // edges per bin-count/bin-place block
#define PNODES 64                   // nodes per wsum block
#define ENC_B (NP / 2 + NL / 2)     // encoder blocks inside init_k

typedef __attribute__((ext_vector_type(8))) short short8;
typedef __attribute__((ext_vector_type(4))) float f32x4;

__device__ __forceinline__ ushort f2bf(float f) {
    uint32_t u = __float_as_uint(f);
    u += 0x7FFFu + ((u >> 16) & 1u);
    return (ushort)(u >> 16);
}
__device__ __forceinline__ float bf2f(ushort h) {
    return __uint_as_float(((uint32_t)h) << 16);
}
__device__ __forceinline__ float bflo(uint32_t v) { return __uint_as_float(v << 16); }
__device__ __forceinline__ float bfhi(uint32_t v) { return __uint_as_float(v & 0xFFFF0000u); }

// ---------------- init: prep_w ∪ encoders ∪ binCount (independent work) ------
__global__ void init_k(const float* __restrict__ Wl1, const float* __restrict__ Wr1,
                       const float* __restrict__ bl1,
                       const float* __restrict__ Wl2, const float* __restrict__ Wr2,
                       const float* __restrict__ bl2,
                       ushort* __restrict__ wlt, float* __restrict__ bsum,
                       const float* __restrict__ xp, const float* __restrict__ Wp,
                       const float* __restrict__ bp,
                       const float* __restrict__ xl, const float* __restrict__ Wle,
                       const float* __restrict__ ble,
                       ushort* __restrict__ hp, ushort* __restrict__ hl,
                       const int* __restrict__ intra_d, const int* __restrict__ inter_d,
                       const int* __restrict__ map_d,
                       int Ei, int Et, int Em, int G1, int* __restrict__ cntMat)
{
    __shared__ int cnt[NB];
    int blk = blockIdx.x;
    int t = threadIdx.x;

    if (blk < 9) {
        int m = blk;
        if (m < 8) {
            int l = m >> 2, r = m & 3;
            const float* Wl = l ? Wl2 : Wl1;
            const float* Wr = l ? Wr2 : Wr1;
            ushort* dst = wlt + (size_t)m * 16384;
            for (int it = 0; it < 64; ++it) {
                int idx = it * 256 + t;
                int k = idx >> 7, n = idx & 127;
                float v;
                if (r < 3) v = Wl[r * 16384 + k * 128 + n];
                else       v = Wr[0 * 16384 + k * 128 + n] + Wr[1 * 16384 + k * 128 + n]
                             + Wr[2 * 16384 + k * 128 + n];
                dst[n * 128 + k] = f2bf(v);
            }
        } else if (t < 128) {
            bsum[t]       = bl1[t] + bl1[128 + t] + bl1[256 + t];
            bsum[128 + t] = bl2[t] + bl2[128 + t] + bl2[256 + t];
        }
    } else if (blk < 9 + ENC_B) {
        int b2 = blk - 9;
        int c = t & 127;
        if (b2 < NP / 2) {
            int i = b2 * 2 + (t >> 7);
            float acc = bp[c];
            for (int k = 0; k < 5; ++k) acc += xp[(size_t)i * 5 + k] * Wp[k * 128 + c];
            hp[(size_t)i * 128 + c] = f2bf(fmaxf(acc, 0.f));
        } else {
            int i = (b2 - NP / 2) * 2 + (t >> 7);
            float acc = ble[c] + xl[i] * Wle[c];
            hl[(size_t)i * 128 + c] = f2bf(fmaxf(acc, 0.f));
        }
    } else {
        int g = blk - 9 - ENC_B;
        for (int b = t; b < NB; b += 256) cnt[b] = 0;
        __syncthreads();
        int Eall = Ei + Et + Em;
        int e0 = g * EPB, e1 = min(e0 + EPB, Eall);
        for (int e = e0 + t; e < e1; e += 256) {
            int d;
            if (e < Ei)           d = intra_d[e];
            else if (e < Ei + Et) d = NP + inter_d[e - Ei];
            else                  d = 2 * NP + map_d[e - Ei - Et];
            atomicAdd(&cnt[d >> 9], 1);
        }
        __syncthreads();
        for (int b = t; b < NB; b += 256) cntMat[b * G1 + g] = cnt[b];
    }
}

// ---------------- hierarchical exclusive scan --------------------------------
__global__ void scanA_k(const int* __restrict__ data, int* __restrict__ partials, int n)
{
    __shared__ int red[256];
    int t = threadIdx.x;
    int idx = blockIdx.x * 256 + t;
    red[t] = (idx < n) ? data[idx] : 0;
    __syncthreads();
    for (int o = 128; o; o >>= 1) { if (t < o) red[t] += red[t + o]; __syncthreads(); }
    if (t == 0) partials[blockIdx.x] = red[0];
}

__global__ void scanB_k(int* __restrict__ partials, int np)
{
    __shared__ int lds[1024];
    int t = threadIdx.x;
    int v0 = (2 * t     < np) ? partials[2 * t]     : 0;
    int v1 = (2 * t + 1 < np) ? partials[2 * t + 1] : 0;
    lds[t] = v0 + v1;
    __syncthreads();
    for (int d = 1; d < 1024; d <<= 1) {
        int v = (t >= d) ? lds[t - d] : 0;
        __syncthreads();
        lds[t] += v;
        __syncthreads();
    }
    int base = (t == 0) ? 0 : lds[t - 1];
    if (2 * t     < np) partials[2 * t]     = base;
    if (2 * t + 1 < np) partials[2 * t + 1] = base + v0;
}

__global__ void scanC_k(int* __restrict__ data, const int* __restrict__ partials, int n)
{
    __shared__ int lds[256];
    int t = threadIdx.x;
    int idx = blockIdx.x * 256 + t;
    int v = (idx < n) ? data[idx] : 0;
    lds[t] = v;
    __syncthreads();
    for (int d = 1; d < 256; d <<= 1) {
        int x = (t >= d) ? lds[t - d] : 0;
        __syncthreads();
        lds[t] += x;
        __syncthreads();
    }
    if (idx < n) data[idx] = lds[t] - v + partials[blockIdx.x];  // exclusive, in-place
}

// P3: place edges as packed uint32 (src<<9 | dst&511) into bucket-grouped array
__global__ void binPlace_k(const int* __restrict__ intra_s, const int* __restrict__ intra_d,
                           const int* __restrict__ inter_s, const int* __restrict__ inter_d,
                           const int* __restrict__ map_s, const int* __restrict__ map_d,
                           int Ei, int Et, int Em, int G1,
                           const int* __restrict__ baseMat, uint32_t* __restrict__ binned)
{
    __shared__ int cur[NB];
    int g = blockIdx.x, t = threadIdx.x;
    for (int b = t; b < NB; b += 256) cur[b] = baseMat[b * G1 + g];
    __syncthreads();
    int Eall = Ei + Et + Em;
    int e0 = g * EPB, e1 = min(e0 + EPB, Eall);
    for (int e = e0 + t; e < e1; e += 256) {
        int s, d;
        if (e < Ei)           { s = intra_s[e];          d = intra_d[e]; }
        else if (e < Ei + Et) { int k = e - Ei;      s = inter_s[k]; d = NP + inter_d[k]; }
        else                  { int k = e - Ei - Et; s = map_s[k];   d = 2 * NP + map_d[k]; }
        int p = atomicAdd(&cur[d >> 9], 1);
        binned[p] = ((uint32_t)s << 9) | (uint32_t)(d & 511);
    }
}

__global__ void csr_k(const uint32_t* __restrict__ binned, const int* __restrict__ baseMat,
                      int G1, int Eall, int* __restrict__ rowptr, int* __restrict__ ss)
{
    __shared__ int hist[BKT], orig[BKT], cur[BKT];
    int b = blockIdx.x, t = threadIdx.x;
    int bs = baseMat[b * G1];
    int be = (b == NB - 1) ? Eall : baseMat[(b + 1) * G1];

    hist[t] = 0; hist[t + 256] = 0;
    __syncthreads();
    for (int e = bs + t; e < be; e += 256) atomicAdd(&hist[binned[e] & 511], 1);
    __syncthreads();
    orig[t] = hist[t]; orig[t + 256] = hist[t + 256];
    __syncthreads();
    for (int d = 1; d < 512; d <<= 1) {
        int v0 = (t >= d) ? hist[t - d] : 0;
        int v1 = hist[t + 256 - d];
        __syncthreads();
        hist[t] += v0; hist[t + 256] += v1;
        __syncthreads();
    }
    int e0 = hist[t] - orig[t];
    int e1 = hist[t + 256] - orig[t + 256];
    cur[t] = e0; cur[t + 256] = e1;
    rowptr[b * BKT + t] = bs + e0;
    rowptr[b * BKT + t + 256] = bs + e1;
    if (b == NB - 1 && t == 0) rowptr[NTOT2] = Eall;
    __syncthreads();
    for (int e = bs + t; e < be; e += 256) {
        uint32_t v = binned[e];
        int p = bs + atomicAdd(&cur[v & 511], 1);
        ss[p] = (int)(v >> 9);
    }
}

// ---------------- gather-means: half-wave per node, 8-deep unroll ------------
// 32 lanes/node, uint2 (4ch)/lane; 2 streams x 8 in-flight rows = 16 rows/wave.
#define GBODY(h)                                                                  \
    int s0 = rowptr[g], s1 = rowptr[g + 1];                                       \
    float a0 = 0.f, a1 = 0.f, a2 = 0.f, a3 = 0.f;                                 \
    int e = s0;                                                                   \
    for (; e + 8 <= s1; e += 8) {                                                 \
        uint2 v0 = *(const uint2*)((h) + (size_t)ssrc[e]     * 128 + lane * 4);   \
        uint2 v1 = *(const uint2*)((h) + (size_t)ssrc[e + 1] * 128 + lane * 4);   \
        uint2 v2 = *(const uint2*)((h) + (size_t)ssrc[e + 2] * 128 + lane * 4);   \
        uint2 v3 = *(const uint2*)((h) + (size_t)ssrc[e + 3] * 128 + lane * 4);   \
        uint2 v4 = *(const uint2*)((h) + (size_t)ssrc[e + 4] * 128 + lane * 4);   \
        uint2 v5 = *(const uint2*)((h) + (size_t)ssrc[e + 5] * 128 + lane * 4);   \
        uint2 v6 = *(const uint2*)((h) + (size_t)ssrc[e + 6] * 128 + lane * 4);   \
        uint2 v7 = *(const uint2*)((h) + (size_t)ssrc[e + 7] * 128 + lane * 4);   \
        a0 += bflo(v0.x) + bflo(v1.x) + bflo(v2.x) + bflo(v3.x)                   \
            + bflo(v4.x) + bflo(v5.x) + bflo(v6.x) + bflo(v7.x);                  \
        a1 += bfhi(v0.x) + bfhi(v1.x) + bfhi(v2.x) + bfhi(v3.x)                   \
            + bfhi(v4.x) + bfhi(v5.x) + bfhi(v6.x) + bfhi(v7.x);                  \
        a2 += bflo(v0.y) + bflo(v1.y) + bflo(v2.y) + bflo(v3.y)                   \
            + bflo(v4.y) + bflo(v5.y) + bflo(v6.y) + bflo(v7.y);                  \
        a3 += bfhi(v0.y) + bfhi(v1.y) + bfhi(v2.y) + bfhi(v3.y)                   \
            + bfhi(v4.y) + bfhi(v5.y) + bfhi(v6.y) + bfhi(v7.y);                  \
    }                                                                             \
    for (; e < s1; ++e) {                                                         \
        uint2 v = *(const uint2*)((h) + (size_t)ssrc[e] * 128 + lane * 4);        \
        a0 += bflo(v.x);                                                          \
        a1 += bfhi(v.x);                                                          \
        a2 += bflo(v.y);                                                          \
        a3 += bfhi(v.y);                                                          \
    }                                                                             \
    float inv = 1.0f / fmaxf((float)(s1 - s0), 1.0f);                             \
    ushort4 o;                                                                    \
    o.x = f2bf(a0 * inv);                                                         \
    o.y = f2bf(a1 * inv);                                                         \
    o.z = f2bf(a2 * inv);                                                         \
    o.w = f2bf(a3 * inv);                                                         \
    *(ushort4*)(out + (size_t)i * 128 + lane * 4) = o;

__global__ void gather3_k(const ushort* __restrict__ hp, const ushort* __restrict__ hl,
                          const int* __restrict__ rowptr, const int* __restrict__ ssrc,
                          ushort* __restrict__ outA, ushort* __restrict__ outB,
                          ushort* __restrict__ outM)
{
    int g = blockIdx.x * 8 + (threadIdx.x >> 5);   // node (concat idx)
    int lane = threadIdx.x & 31;
    const ushort* h; ushort* out; int i;
    if (g < NP)          { h = hp; out = outA; i = g; }
    else if (g < 2 * NP) { h = hp; out = outB; i = g - NP; }
    else                 { h = hl; out = outM; i = g - 2 * NP; }
    GBODY(h)
}

__global__ void gather2_k(const ushort* __restrict__ hp, const int* __restrict__ rowptr,
                          const int* __restrict__ ssrc,
                          ushort* __restrict__ outA, ushort* __restrict__ outB)
{
    int g = blockIdx.x * 8 + (threadIdx.x >> 5);
    int lane = threadIdx.x & 31;
    ushort* out = (g < NP) ? outA : outB;
    int i = (g < NP) ? g : (g - NP);
    GBODY(hp)
}

// ---------------- 4-source GEMM, LDS-staged (proven round-9 structure) -------
__launch_bounds__(256, 2)
__global__ void gemm_k(const ushort* __restrict__ A0, const ushort* __restrict__ A1,
                       const ushort* __restrict__ A2, const ushort* __restrict__ A3,
                       const ushort* __restrict__ W0, const ushort* __restrict__ W1,
                       const ushort* __restrict__ W2, const ushort* __restrict__ W3,
                       const float* __restrict__ bias, ushort* __restrict__ out,
                       const float* __restrict__ Wg, const float* __restrict__ bg,
                       float* __restrict__ gateOut)
{
    __shared__ ushort a_lds[128][72];
    __shared__ ushort w_lds[128][72];
    __shared__ float gacc[128];
    const int tid = threadIdx.x;
    const int lane = tid & 63, wave = tid >> 6;
    const int wr = wave >> 1, wc = wave & 1;
    const size_t r0 = (size_t)blockIdx.x * 128;

    if (tid < 128) gacc[tid] = 0.f;

    f32x4 acc[4][4];
    const f32x4 zero = {0.f, 0.f, 0.f, 0.f};
#pragma unroll
    for (int m = 0; m < 4; ++m)
#pragma unroll
        for (int n = 0; n < 4; ++n) acc[m][n] = zero;

    const ushort* As[4] = {A0, A1, A2, A3};
    const ushort* Ws[4] = {W0, W1, W2, W3};

    for (int s = 0; s < 4; ++s) {
        const ushort* Ap = As[s] + r0 * 128;
        const ushort* Wp = Ws[s];
        for (int k0 = 0; k0 < 128; k0 += 64) {
            __syncthreads();
#pragma unroll
            for (int j = 0; j < 4; ++j) {
                int idx = (j * 256 + tid) * 8;
                int r = idx >> 6, c = idx & 63;
                *(uint4*)&a_lds[r][c] = *(const uint4*)(Ap + r * 128 + k0 + c);
                *(uint4*)&w_lds[r][c] = *(const uint4*)(Wp + r * 128 + k0 + c);
            }
            __syncthreads();
#pragma unroll
            for (int ks = 0; ks < 64; ks += 32) {
                short8 af[4], bfr[4];
                int col = ks + ((lane >> 4) << 3);
                int ra = (wr << 6) + (lane & 15);
                int rb = (wc << 6) + (lane & 15);
#pragma unroll
                for (int m = 0; m < 4; ++m) af[m] = *(const short8*)&a_lds[ra + m * 16][col];
#pragma unroll
                for (int n = 0; n < 4; ++n) bfr[n] = *(const short8*)&w_lds[rb + n * 16][col];
#pragma unroll
                for (int m = 0; m < 4; ++m)
#pragma unroll
                    for (int n = 0; n < 4; ++n)
                        acc[m][n] = __builtin_amdgcn_mfma_f32_16x16x32_bf16(
                            af[m], bfr[n], acc[m][n], 0, 0, 0);
            }
        }
    }

    const int rbase = (wr << 6) + ((lane >> 4) << 2);
    const int cbase = (wc << 6) + (lane & 15);
    float bcol[4], wg4[4];
#pragma unroll
    for (int n = 0; n < 4; ++n) {
        bcol[n] = bias[cbase + n * 16];
        wg4[n] = gateOut ? Wg[cbase + n * 16] : 0.f;
    }
#pragma unroll
    for (int m = 0; m < 4; ++m)
#pragma unroll
        for (int rg = 0; rg < 4; ++rg) {
            int row = rbase + m * 16 + rg;
            float p = 0.f;
#pragma unroll
            for (int n = 0; n < 4; ++n) {
                float v = fmaxf(acc[m][n][rg] + bcol[n], 0.f);
                out[(r0 + row) * 128 + cbase + n * 16] = f2bf(v);
                p += v * wg4[n];
            }
            if (gateOut) {
#pragma unroll
                for (int o = 1; o < 16; o <<= 1) p += __shfl_xor(p, o);
                if ((lane & 15) == 0) atomicAdd(&gacc[row], p);
            }
        }
    if (gateOut) {
        __syncthreads();
        if (tid < 128) gateOut[r0 + tid] = gacc[tid] + bg[0];
    }
}

// ---------------- per-batch softmax stats: m[b], 1/den[b]; zeroes emb --------
__global__ void seg_stat_k(const float* __restrict__ gate, const int* __restrict__ batch,
                           float* __restrict__ mden, float* __restrict__ emb)
{
    __shared__ float red[256];
    __shared__ int sb[2];
    __shared__ float sm;
    int b = blockIdx.x, t = threadIdx.x;
    if (t < 128) emb[b * 128 + t] = 0.f;
    if (t < 2) {
        int target = b + t;
        int lo = 0, hi = NP;
        while (lo < hi) { int mid = (lo + hi) >> 1; if (batch[mid] < target) lo = mid + 1; else hi = mid; }
        sb[t] = lo;
    }
    __syncthreads();
    int s = sb[0], e = sb[1];

    float lm = -3.4e38f;
    for (int i = s + t; i < e; i += 256) lm = fmaxf(lm, gate[i]);
    red[t] = lm; __syncthreads();
    for (int o = 128; o; o >>= 1) { if (t < o) red[t] = fmaxf(red[t], red[t + o]); __syncthreads(); }
    if (t == 0) sm = red[0];
    __syncthreads();
    float m = sm;

    float loc = 0.f;
    for (int i = s + t; i < e; i += 256) loc += __expf(gate[i] - m);
    red[t] = loc; __syncthreads();
    for (int o = 128; o; o >>= 1) { if (t < o) red[t] += red[t + o]; __syncthreads(); }
    if (t == 0) {
        mden[b] = m;
        mden[NBAT + b] = (e > s) ? 1.0f / red[0] : 0.f;
    }
}

// ---------------- weighted segment sum: emb[b] += alpha_i * h_p[i] -----------
__global__ void wsum_k(const ushort* __restrict__ hp, const float* __restrict__ gate,
                       const int* __restrict__ batch, const float* __restrict__ mden,
                       float* __restrict__ emb)
{
    int n0 = blockIdx.x * PNODES;
    int t = threadIdx.x;
    int c2 = (t & 63) * 2;
    int slice = t >> 6;
    float a0 = 0.f, a1 = 0.f;
    int curb = batch[n0 + slice];
    for (int i = n0 + slice; i < n0 + PNODES; i += 4) {
        int b = batch[i];
        if (b != curb) {
            atomicAdd(&emb[curb * 128 + c2], a0);
            atomicAdd(&emb[curb * 128 + c2 + 1], a1);
            a0 = a1 = 0.f;
            curb = b;
        }
        float w = __expf(gate[i] - mden[curb]) * mden[NBAT + curb];
        uint32_t v = *(const uint32_t*)(hp + (size_t)i * 128 + c2);
        a0 += w * bflo(v);
        a1 += w * bfhi(v);
    }
    atomicAdd(&emb[curb * 128 + c2], a0);
    atomicAdd(&emb[curb * 128 + c2 + 1], a1);
}

// ---------------- actor/critic heads ----------------------------------------
__global__ void heads_k(const float* __restrict__ emb,
                        const float* __restrict__ Wa1, const float* __restrict__ ba1,
                        const float* __restrict__ Wa2, const float* __restrict__ ba2,
                        const float* __restrict__ Wc1, const float* __restrict__ bc1,
                        const float* __restrict__ Wc2, const float* __restrict__ bc2,
                        float* __restrict__ outL, float* __restrict__ outV)
{
    __shared__ float er[128], ha[128], hc[128], red[128];
    int b = blockIdx.x, t = threadIdx.x;
    if (t < 128) er[t] = emb[b * 128 + t];
    __syncthreads();
    if (t < 128) {
        float a = ba1[t];
        for (int k = 0; k < 128; ++k) a += er[k] * Wa1[k * 128 + t];
        ha[t] = fmaxf(a, 0.f);
    } else {
        int c = t - 128;
        float a = bc1[c];
        for (int k = 0; k < 128; ++k) a += er[k] * Wc1[k * 128 + c];
        hc[c] = fmaxf(a, 0.f);
    }
    __syncthreads();
    {
        float a = ba2[t];
        for (int k = 0; k < 128; ++k) a += ha[k] * Wa2[k * 256 + t];
        outL[b * 256 + t] = a;
    }
    if (t < 128) red[t] = hc[t] * Wc2[t];
    __syncthreads();
    for (int o = 64; o; o >>= 1) { if (t < o) red[t] += red[t + o]; __syncthreads(); }
    if (t == 0) outV[b] = red[0] + bc2[0];
}

// ============================================================================
extern "C" void kernel_launch(void* const* d_in, const int* in_sizes, int n_in,
                              void* d_out, int out_size, void* d_ws, size_t ws_size,
                              hipStream_t stream)
{
    const float* x_phys = (const float*)d_in[0];
    const float* x_log  = (const float*)d_in[1];
    const int*   batch  = (const int*)d_in[3];
    const int* intra_s = (const int*)d_in[4];  const int* intra_d = (const int*)d_in[5];
    const int* inter_s = (const int*)d_in[6];  const int* inter_d = (const int*)d_in[7];
    const int* map_s   = (const int*)d_in[8];  const int* map_d   = (const int*)d_in[9];
    const int E_INTRA = in_sizes[4], E_INTER = in_sizes[6], E_MAP = in_sizes[8];
    const int E_ALL = E_INTRA + E_INTER + E_MAP;

    const float* W_phys = (const float*)d_in[14]; const float* b_phys = (const float*)d_in[15];
    const float* W_log  = (const float*)d_in[16]; const float* b_log  = (const float*)d_in[17];
    const float* Wl1 = (const float*)d_in[20]; const float* bl1 = (const float*)d_in[21];
    const float* Wr1 = (const float*)d_in[22];
    const float* Wl2 = (const float*)d_in[23]; const float* bl2 = (const float*)d_in[24];
    const float* Wr2 = (const float*)d_in[25];
    const float* Wg  = (const float*)d_in[26]; const float* bg  = (const float*)d_in[27];
    const float* Wa1 = (const float*)d_in[28]; const float* ba1 = (const float*)d_in[29];
    const float* Wa2 = (const float*)d_in[30]; const float* ba2 = (const float*)d_in[31];
    const float* Wc1 = (const float*)d_in[32]; const float* bc1 = (const float*)d_in[33];
    const float* Wc2 = (const float*)d_in[34]; const float* bc2 = (const float*)d_in[35];

    float* outL = (float*)d_out;
    float* outV = outL + NBAT * AD;

    // ---- carve workspace ----
    char* wsp = (char*)d_ws;
    size_t off = 0;
    auto alloc = [&](size_t sz) -> void* {
        void* p = wsp + off;
        off = (off + sz + 255) & ~(size_t)255;
        return p;
    };
    ushort* hp    = (ushort*)alloc((size_t)NP * 128 * 2);
    ushort* hl    = (ushort*)alloc((size_t)NL * 128 * 2);
    ushort* aggbA = (ushort*)alloc((size_t)NP * 128 * 2);
    ushort* aggbB = (ushort*)alloc((size_t)NP * 128 * 2);
    ushort* Mmap  = (ushort*)alloc((size_t)NP * 128 * 2);

    // counting-sort CSR structures
    const int G1 = (E_ALL + EPB - 1) / EPB;
    const int NSC = NB * G1;
    const int NPARTS = (NSC + 255) / 256;
    int*      cntMat   = (int*)alloc((size_t)NSC * 4);
    int*      partials = (int*)alloc((size_t)NPARTS * 4);
    uint32_t* binned   = (uint32_t*)alloc((size_t)E_ALL * 4);
    int*      rowptr   = (int*)alloc((size_t)(NTOT2 + 1) * 4);
    int*      ss       = (int*)alloc((size_t)E_ALL * 4);

    float*  gate = (float*)alloc((size_t)NP * 4);
    float*  mden = (float*)alloc(2 * NBAT * 4);
    float*  emb  = (float*)alloc(NBAT * 128 * 4);
    ushort* wlt  = (ushort*)alloc((size_t)2 * 4 * 16384 * 2);
    float*  bsum = (float*)alloc(2 * 128 * 4);
    (void)ws_size; (void)out_size; (void)n_in;

    // ---- init: weight prep + encoders + binCount in ONE launch ----
    init_k<<<9 + ENC_B + G1, 256, 0, stream>>>(
        Wl1, Wr1, bl1, Wl2, Wr2, bl2, wlt, bsum,
        x_phys, W_phys, b_phys, x_log, W_log, b_log, hp, hl,
        intra_d, inter_d, map_d, E_INTRA, E_INTER, E_MAP, G1, cntMat);

    // ---- CSR build via LDS counting sort (once; reused both layers) ----
    scanA_k<<<NPARTS, 256, 0, stream>>>(cntMat, partials, NSC);
    scanB_k<<<1, 1024, 0, stream>>>(partials, NPARTS);
    scanC_k<<<NPARTS, 256, 0, stream>>>(cntMat, partials, NSC);
    binPlace_k<<<G1, 256, 0, stream>>>(intra_s, intra_d, inter_s, inter_d, map_s, map_d,
                                       E_INTRA, E_INTER, E_MAP, G1, cntMat, binned);
    csr_k<<<NB, 256, 0, stream>>>(binned, cntMat, G1, E_ALL, rowptr, ss);

    // ---- layer 1: merged gather (intra, inter, map) + GEMM ----
    gather3_k<<<3 * NP / 8, 256, 0, stream>>>(hp, hl, rowptr, ss, aggbA, aggbB, Mmap);
    gemm_k<<<NP / 128, 256, 0, stream>>>(aggbA, aggbB, Mmap, hp,
                                         wlt + 0 * 16384, wlt + 1 * 16384,
                                         wlt + 2 * 16384, wlt + 3 * 16384,
                                         bsum, hp, nullptr, nullptr, nullptr);

    // ---- layer 2: gather (intra, inter; Mmap reused) + GEMM + fused gate ----
    gather2_k<<<2 * NP / 8, 256, 0, stream>>>(hp, rowptr, ss, aggbA, aggbB);
    gemm_k<<<NP / 128, 256, 0, stream>>>(aggbA, aggbB, Mmap, hp,
                                         wlt + 4 * 16384, wlt + 5 * 16384,
                                         wlt + 6 * 16384, wlt + 7 * 16384,
                                         bsum + 128, hp, Wg, bg, gate);

    // ---- attentional pooling + heads ----
    seg_stat_k<<<NBAT, 256, 0, stream>>>(gate, batch, mden, emb);
    wsum_k<<<NP / PNODES, 256, 0, stream>>>(hp, gate, batch, mden, emb);
    heads_k<<<NBAT, 256, 0, stream>>>(emb, Wa1, ba1, Wa2, ba2, Wc1, bc1, Wc2, bc2, outL, outV);
}

// Round 16
// 250.490 us; speedup vs baseline: 1.1035x; 1.1035x over previous
//
#include <hip/hip_runtime.h>
#include <stdint.h>

#define H    128
#define NBAT 128
#define AD   256
#define NP   65536
#define NL   32768
#define NTOT2 (3 * NP)              // intra | inter | map concatenated CSR nodes
#define NB   384                    // coarse buckets (dst >> 9)
#define BKT  512                    // nodes per bucket
#define EPB  4096                   // edges per bin-count/bin-place block
#define PNODES 64                   // nodes per wsum block
#define ENC_B (NP / 2 + NL / 2)     // encoder blocks inside init_k

typedef __attribute__((ext_vector_type(8))) short short8;
typedef __attribute__((ext_vector_type(4))) float f32x4;

__device__ __forceinline__ ushort f2bf(float f) {
    uint32_t u = __float_as_uint(f);
    u += 0x7FFFu + ((u >> 16) & 1u);
    return (ushort)(u >> 16);
}
__device__ __forceinline__ float bf2f(ushort h) {
    return __uint_as_float(((uint32_t)h) << 16);
}
__device__ __forceinline__ float bflo(uint32_t v) { return __uint_as_float(v << 16); }
__device__ __forceinline__ float bfhi(uint32_t v) { return __uint_as_float(v & 0xFFFF0000u); }

// ---------------- init: prep_w ∪ encoders ∪ binCount (independent work) ------
__global__ void init_k(const float* __restrict__ Wl1, const float* __restrict__ Wr1,
                       const float* __restrict__ bl1,
                       const float* __restrict__ Wl2, const float* __restrict__ Wr2,
                       const float* __restrict__ bl2,
                       ushort* __restrict__ wlt, float* __restrict__ bsum,
                       const float* __restrict__ xp, const float* __restrict__ Wp,
                       const float* __restrict__ bp,
                       const float* __restrict__ xl, const float* __restrict__ Wle,
                       const float* __restrict__ ble,
                       ushort* __restrict__ hp, ushort* __restrict__ hl,
                       const int* __restrict__ intra_d, const int* __restrict__ inter_d,
                       const int* __restrict__ map_d,
                       int Ei, int Et, int Em, int G1, int* __restrict__ cntMat)
{
    __shared__ int cnt[NB];
    int blk = blockIdx.x;
    int t = threadIdx.x;

    if (blk < 9) {
        int m = blk;
        if (m < 8) {
            int l = m >> 2, r = m & 3;
            const float* Wl = l ? Wl2 : Wl1;
            const float* Wr = l ? Wr2 : Wr1;
            ushort* dst = wlt + (size_t)m * 16384;
            for (int it = 0; it < 64; ++it) {
                int idx = it * 256 + t;
                int k = idx >> 7, n = idx & 127;
                float v;
                if (r < 3) v = Wl[r * 16384 + k * 128 + n];
                else       v = Wr[0 * 16384 + k * 128 + n] + Wr[1 * 16384 + k * 128 + n]
                             + Wr[2 * 16384 + k * 128 + n];
                dst[n * 128 + k] = f2bf(v);
            }
        } else if (t < 128) {
            bsum[t]       = bl1[t] + bl1[128 + t] + bl1[256 + t];
            bsum[128 + t] = bl2[t] + bl2[128 + t] + bl2[256 + t];
        }
    } else if (blk < 9 + ENC_B) {
        int b2 = blk - 9;
        int c = t & 127;
        if (b2 < NP / 2) {
            int i = b2 * 2 + (t >> 7);
            float acc = bp[c];
            for (int k = 0; k < 5; ++k) acc += xp[(size_t)i * 5 + k] * Wp[k * 128 + c];
            hp[(size_t)i * 128 + c] = f2bf(fmaxf(acc, 0.f));
        } else {
            int i = (b2 - NP / 2) * 2 + (t >> 7);
            float acc = ble[c] + xl[i] * Wle[c];
            hl[(size_t)i * 128 + c] = f2bf(fmaxf(acc, 0.f));
        }
    } else {
        int g = blk - 9 - ENC_B;
        for (int b = t; b < NB; b += 256) cnt[b] = 0;
        __syncthreads();
        int Eall = Ei + Et + Em;
        int e0 = g * EPB, e1 = min(e0 + EPB, Eall);
        for (int e = e0 + t; e < e1; e += 256) {
            int d;
            if (e < Ei)           d = intra_d[e];
            else if (e < Ei + Et) d = NP + inter_d[e - Ei];
            else                  d = 2 * NP + map_d[e - Ei - Et];
            atomicAdd(&cnt[d >> 9], 1);
        }
        __syncthreads();
        for (int b = t; b < NB; b += 256) cntMat[b * G1 + g] = cnt[b];
    }
}

// ---------------- hierarchical exclusive scan --------------------------------
__global__ void scanA_k(const int* __restrict__ data, int* __restrict__ partials, int n)
{
    __shared__ int red[256];
    int t = threadIdx.x;
    int idx = blockIdx.x * 256 + t;
    red[t] = (idx < n) ? data[idx] : 0;
    __syncthreads();
    for (int o = 128; o; o >>= 1) { if (t < o) red[t] += red[t + o]; __syncthreads(); }
    if (t == 0) partials[blockIdx.x] = red[0];
}

__global__ void scanB_k(int* __restrict__ partials, int np)
{
    __shared__ int lds[1024];
    int t = threadIdx.x;
    int v0 = (2 * t     < np) ? partials[2 * t]     : 0;
    int v1 = (2 * t + 1 < np) ? partials[2 * t + 1] : 0;
    lds[t] = v0 + v1;
    __syncthreads();
    for (int d = 1; d < 1024; d <<= 1) {
        int v = (t >= d) ? lds[t - d] : 0;
        __syncthreads();
        lds[t] += v;
        __syncthreads();
    }
    int base = (t == 0) ? 0 : lds[t - 1];
    if (2 * t     < np) partials[2 * t]     = base;
    if (2 * t + 1 < np) partials[2 * t + 1] = base + v0;
}

__global__ void scanC_k(int* __restrict__ data, const int* __restrict__ partials, int n)
{
    __shared__ int lds[256];
    int t = threadIdx.x;
    int idx = blockIdx.x * 256 + t;
    int v = (idx < n) ? data[idx] : 0;
    lds[t] = v;
    __syncthreads();
    for (int d = 1; d < 256; d <<= 1) {
        int x = (t >= d) ? lds[t - d] : 0;
        __syncthreads();
        lds[t] += x;
        __syncthreads();
    }
    if (idx < n) data[idx] = lds[t] - v + partials[blockIdx.x];  // exclusive, in-place
}

// P3: place edges as packed uint32 (src<<9 | dst&511) into bucket-grouped array
__global__ void binPlace_k(const int* __restrict__ intra_s, const int* __restrict__ intra_d,
                           const int* __restrict__ inter_s, const int* __restrict__ inter_d,
                           const int* __restrict__ map_s, const int* __restrict__ map_d,
                           int Ei, int Et, int Em, int G1,
                           const int* __restrict__ baseMat, uint32_t* __restrict__ binned)
{
    __shared__ int cur[NB];
    int g = blockIdx.x, t = threadIdx.x;
    for (int b = t; b < NB; b += 256) cur[b] = baseMat[b * G1 + g];
    __syncthreads();
    int Eall = Ei + Et + Em;
    int e0 = g * EPB, e1 = min(e0 + EPB, Eall);
    for (int e = e0 + t; e < e1; e += 256) {
        int s, d;
        if (e < Ei)           { s = intra_s[e];          d = intra_d[e]; }
        else if (e < Ei + Et) { int k = e - Ei;      s = inter_s[k]; d = NP + inter_d[k]; }
        else                  { int k = e - Ei - Et; s = map_s[k];   d = 2 * NP + map_d[k]; }
        int p = atomicAdd(&cur[d >> 9], 1);
        binned[p] = ((uint32_t)s << 9) | (uint32_t)(d & 511);
    }
}

__global__ void csr_k(const uint32_t* __restrict__ binned, const int* __restrict__ baseMat,
                      int G1, int Eall, int* __restrict__ rowptr, int* __restrict__ ss)
{
    __shared__ int hist[BKT], orig[BKT], cur[BKT];
    int b = blockIdx.x, t = threadIdx.x;
    int bs = baseMat[b * G1];
    int be = (b == NB - 1) ? Eall : baseMat[(b + 1) * G1];

    hist[t] = 0; hist[t + 256] = 0;
    __syncthreads();
    for (int e = bs + t; e < be; e += 256) atomicAdd(&hist[binned[e] & 511], 1);
    __syncthreads();
    orig[t] = hist[t]; orig[t + 256] = hist[t + 256];
    __syncthreads();
    for (int d = 1; d < 512; d <<= 1) {
        int v0 = (t >= d) ? hist[t - d] : 0;
        int v1 = hist[t + 256 - d];
        __syncthreads();
        hist[t] += v0; hist[t + 256] += v1;
        __syncthreads();
    }
    int e0 = hist[t] - orig[t];
    int e1 = hist[t + 256] - orig[t + 256];
    cur[t] = e0; cur[t + 256] = e1;
    rowptr[b * BKT + t] = bs + e0;
    rowptr[b * BKT + t + 256] = bs + e1;
    if (b == NB - 1 && t == 0) rowptr[NTOT2] = Eall;
    __syncthreads();
    for (int e = bs + t; e < be; e += 256) {
        uint32_t v = binned[e];
        int p = bs + atomicAdd(&cur[v & 511], 1);
        ss[p] = (int)(v >> 9);
    }
}

// ---------------- gather-means: QUARTER-WAVE per node, unroll-4 --------------
// 16 lanes/node, uint4 (8ch)/lane; 4 node streams/wave -> 16 rows in flight in
// the main loop, 4 in the remainder (covers inter deg~4 and map deg~1).
#define GBODY(h)                                                                  \
    int s0 = rowptr[g], s1 = rowptr[g + 1];                                       \
    float a0 = 0.f, a1 = 0.f, a2 = 0.f, a3 = 0.f,                                 \
          a4 = 0.f, a5 = 0.f, a6 = 0.f, a7 = 0.f;                                 \
    int e = s0;                                                                   \
    for (; e + 4 <= s1; e += 4) {                                                 \
        uint4 v0 = *(const uint4*)((h) + (size_t)ssrc[e]     * 128 + lane * 8);   \
        uint4 v1 = *(const uint4*)((h) + (size_t)ssrc[e + 1] * 128 + lane * 8);   \
        uint4 v2 = *(const uint4*)((h) + (size_t)ssrc[e + 2] * 128 + lane * 8);   \
        uint4 v3 = *(const uint4*)((h) + (size_t)ssrc[e + 3] * 128 + lane * 8);   \
        a0 += bflo(v0.x) + bflo(v1.x) + bflo(v2.x) + bflo(v3.x);                  \
        a1 += bfhi(v0.x) + bfhi(v1.x) + bfhi(v2.x) + bfhi(v3.x);                  \
        a2 += bflo(v0.y) + bflo(v1.y) + bflo(v2.y) + bflo(v3.y);                  \
        a3 += bfhi(v0.y) + bfhi(v1.y) + bfhi(v2.y) + bfhi(v3.y);                  \
        a4 += bflo(v0.z) + bflo(v1.z) + bflo(v2.z) + bflo(v3.z);                  \
        a5 += bfhi(v0.z) + bfhi(v1.z) + bfhi(v2.z) + bfhi(v3.z);                  \
        a6 += bflo(v0.w) + bflo(v1.w) + bflo(v2.w) + bflo(v3.w);                  \
        a7 += bfhi(v0.w) + bfhi(v1.w) + bfhi(v2.w) + bfhi(v3.w);                  \
    }                                                                             \
    for (; e < s1; ++e) {                                                         \
        uint4 v = *(const uint4*)((h) + (size_t)ssrc[e] * 128 + lane * 8);        \
        a0 += bflo(v.x); a1 += bfhi(v.x);                                         \
        a2 += bflo(v.y); a3 += bfhi(v.y);                                         \
        a4 += bflo(v.z); a5 += bfhi(v.z);                                         \
        a6 += bflo(v.w); a7 += bfhi(v.w);                                         \
    }                                                                             \
    float inv = 1.0f / fmaxf((float)(s1 - s0), 1.0f);                             \
    ushort ov[8];                                                                 \
    ov[0] = f2bf(a0 * inv); ov[1] = f2bf(a1 * inv);                               \
    ov[2] = f2bf(a2 * inv); ov[3] = f2bf(a3 * inv);                               \
    ov[4] = f2bf(a4 * inv); ov[5] = f2bf(a5 * inv);                               \
    ov[6] = f2bf(a6 * inv); ov[7] = f2bf(a7 * inv);                               \
    *(uint4*)(out + (size_t)i * 128 + lane * 8) = *(const uint4*)ov;

__global__ void gather3_k(const ushort* __restrict__ hp, const ushort* __restrict__ hl,
                          const int* __restrict__ rowptr, const int* __restrict__ ssrc,
                          ushort* __restrict__ outA, ushort* __restrict__ outB,
                          ushort* __restrict__ outM)
{
    int g = blockIdx.x * 16 + (threadIdx.x >> 4);   // node (concat idx)
    int lane = threadIdx.x & 15;
    const ushort* h; ushort* out; int i;
    if (g < NP)          { h = hp; out = outA; i = g; }
    else if (g < 2 * NP) { h = hp; out = outB; i = g - NP; }
    else                 { h = hl; out = outM; i = g - 2 * NP; }
    GBODY(h)
}

__global__ void gather2_k(const ushort* __restrict__ hp, const int* __restrict__ rowptr,
                          const int* __restrict__ ssrc,
                          ushort* __restrict__ outA, ushort* __restrict__ outB)
{
    int g = blockIdx.x * 16 + (threadIdx.x >> 4);
    int lane = threadIdx.x & 15;
    ushort* out = (g < NP) ? outA : outB;
    int i = (g < NP) ? g : (g - NP);
    GBODY(hp)
}

// ---------------- 4-source GEMM, LDS-staged (proven round-9 structure) -------
__launch_bounds__(256, 2)
__global__ void gemm_k(const ushort* __restrict__ A0, const ushort* __restrict__ A1,
                       const ushort* __restrict__ A2, const ushort* __restrict__ A3,
                       const ushort* __restrict__ W0, const ushort* __restrict__ W1,
                       const ushort* __restrict__ W2, const ushort* __restrict__ W3,
                       const float* __restrict__ bias, ushort* __restrict__ out,
                       const float* __restrict__ Wg, const float* __restrict__ bg,
                       float* __restrict__ gateOut)
{
    __shared__ ushort a_lds[128][72];
    __shared__ ushort w_lds[128][72];
    __shared__ float gacc[128];
    const int tid = threadIdx.x;
    const int lane = tid & 63, wave = tid >> 6;
    const int wr = wave >> 1, wc = wave & 1;
    const size_t r0 = (size_t)blockIdx.x * 128;

    if (tid < 128) gacc[tid] = 0.f;

    f32x4 acc[4][4];
    const f32x4 zero = {0.f, 0.f, 0.f, 0.f};
#pragma unroll
    for (int m = 0; m < 4; ++m)
#pragma unroll
        for (int n = 0; n < 4; ++n) acc[m][n] = zero;

    const ushort* As[4] = {A0, A1, A2, A3};
    const ushort* Ws[4] = {W0, W1, W2, W3};

    for (int s = 0; s < 4; ++s) {
        const ushort* Ap = As[s] + r0 * 128;
        const ushort* Wp = Ws[s];
        for (int k0 = 0; k0 < 128; k0 += 64) {
            __syncthreads();
#pragma unroll
            for (int j = 0; j < 4; ++j) {
                int idx = (j * 256 + tid) * 8;
                int r = idx >> 6, c = idx & 63;
                *(uint4*)&a_lds[r][c] = *(const uint4*)(Ap + r * 128 + k0 + c);
                *(uint4*)&w_lds[r][c] = *(const uint4*)(Wp + r * 128 + k0 + c);
            }
            __syncthreads();
#pragma unroll
            for (int ks = 0; ks < 64; ks += 32) {
                short8 af[4], bfr[4];
                int col = ks + ((lane >> 4) << 3);
                int ra = (wr << 6) + (lane & 15);
                int rb = (wc << 6) + (lane & 15);
#pragma unroll
                for (int m = 0; m < 4; ++m) af[m] = *(const short8*)&a_lds[ra + m * 16][col];
#pragma unroll
                for (int n = 0; n < 4; ++n) bfr[n] = *(const short8*)&w_lds[rb + n * 16][col];
#pragma unroll
                for (int m = 0; m < 4; ++m)
#pragma unroll
                    for (int n = 0; n < 4; ++n)
                        acc[m][n] = __builtin_amdgcn_mfma_f32_16x16x32_bf16(
                            af[m], bfr[n], acc[m][n], 0, 0, 0);
            }
        }
    }

    const int rbase = (wr << 6) + ((lane >> 4) << 2);
    const int cbase = (wc << 6) + (lane & 15);
    float bcol[4], wg4[4];
#pragma unroll
    for (int n = 0; n < 4; ++n) {
        bcol[n] = bias[cbase + n * 16];
        wg4[n] = gateOut ? Wg[cbase + n * 16] : 0.f;
    }
#pragma unroll
    for (int m = 0; m < 4; ++m)
#pragma unroll
        for (int rg = 0; rg < 4; ++rg) {
            int row = rbase + m * 16 + rg;
            float p = 0.f;
#pragma unroll
            for (int n = 0; n < 4; ++n) {
                float v = fmaxf(acc[m][n][rg] + bcol[n], 0.f);
                out[(r0 + row) * 128 + cbase + n * 16] = f2bf(v);
                p += v * wg4[n];
            }
            if (gateOut) {
#pragma unroll
                for (int o = 1; o < 16; o <<= 1) p += __shfl_xor(p, o);
                if ((lane & 15) == 0) atomicAdd(&gacc[row], p);
            }
        }
    if (gateOut) {
        __syncthreads();
        if (tid < 128) gateOut[r0 + tid] = gacc[tid] + bg[0];
    }
}

// ---------------- per-batch softmax stats: m[b], 1/den[b]; zeroes emb --------
__global__ void seg_stat_k(const float* __restrict__ gate, const int* __restrict__ batch,
                           float* __restrict__ mden, float* __restrict__ emb)
{
    __shared__ float red[256];
    __shared__ int sb[2];
    __shared__ float sm;
    int b = blockIdx.x, t = threadIdx.x;
    if (t < 128) emb[b * 128 + t] = 0.f;
    if (t < 2) {
        int target = b + t;
        int lo = 0, hi = NP;
        while (lo < hi) { int mid = (lo + hi) >> 1; if (batch[mid] < target) lo = mid + 1; else hi = mid; }
        sb[t] = lo;
    }
    __syncthreads();
    int s = sb[0], e = sb[1];

    float lm = -3.4e38f;
    for (int i = s + t; i < e; i += 256) lm = fmaxf(lm, gate[i]);
    red[t] = lm; __syncthreads();
    for (int o = 128; o; o >>= 1) { if (t < o) red[t] = fmaxf(red[t], red[t + o]); __syncthreads(); }
    if (t == 0) sm = red[0];
    __syncthreads();
    float m = sm;

    float loc = 0.f;
    for (int i = s + t; i < e; i += 256) loc += __expf(gate[i] - m);
    red[t] = loc; __syncthreads();
    for (int o = 128; o; o >>= 1) { if (t < o) red[t] += red[t + o]; __syncthreads(); }
    if (t == 0) {
        mden[b] = m;
        mden[NBAT + b] = (e > s) ? 1.0f / red[0] : 0.f;
    }
}

// ---------------- weighted segment sum: emb[b] += alpha_i * h_p[i] -----------
__global__ void wsum_k(const ushort* __restrict__ hp, const float* __restrict__ gate,
                       const int* __restrict__ batch, const float* __restrict__ mden,
                       float* __restrict__ emb)
{
    int n0 = blockIdx.x * PNODES;
    int t = threadIdx.x;
    int c2 = (t & 63) * 2;
    int slice = t >> 6;
    float a0 = 0.f, a1 = 0.f;
    int curb = batch[n0 + slice];
    for (int i = n0 + slice; i < n0 + PNODES; i += 4) {
        int b = batch[i];
        if (b != curb) {
            atomicAdd(&emb[curb * 128 + c2], a0);
            atomicAdd(&emb[curb * 128 + c2 + 1], a1);
            a0 = a1 = 0.f;
            curb = b;
        }
        float w = __expf(gate[i] - mden[curb]) * mden[NBAT + curb];
        uint32_t v = *(const uint32_t*)(hp + (size_t)i * 128 + c2);
        a0 += w * bflo(v);
        a1 += w * bfhi(v);
    }
    atomicAdd(&emb[curb * 128 + c2], a0);
    atomicAdd(&emb[curb * 128 + c2 + 1], a1);
}

// ---------------- actor/critic heads ----------------------------------------
__global__ void heads_k(const float* __restrict__ emb,
                        const float* __restrict__ Wa1, const float* __restrict__ ba1,
                        const float* __restrict__ Wa2, const float* __restrict__ ba2,
                        const float* __restrict__ Wc1, const float* __restrict__ bc1,
                        const float* __restrict__ Wc2, const float* __restrict__ bc2,
                        float* __restrict__ outL, float* __restrict__ outV)
{
    __shared__ float er[128], ha[128], hc[128], red[128];
    int b = blockIdx.x, t = threadIdx.x;
    if (t < 128) er[t] = emb[b * 128 + t];
    __syncthreads();
    if (t < 128) {
        float a = ba1[t];
        for (int k = 0; k < 128; ++k) a += er[k] * Wa1[k * 128 + t];
        ha[t] = fmaxf(a, 0.f);
    } else {
        int c = t - 128;
        float a = bc1[c];
        for (int k = 0; k < 128; ++k) a += er[k] * Wc1[k * 128 + c];
        hc[c] = fmaxf(a, 0.f);
    }
    __syncthreads();
    {
        float a = ba2[t];
        for (int k = 0; k < 128; ++k) a += ha[k] * Wa2[k * 256 + t];
        outL[b * 256 + t] = a;
    }
    if (t < 128) red[t] = hc[t] * Wc2[t];
    __syncthreads();
    for (int o = 64; o; o >>= 1) { if (t < o) red[t] += red[t + o]; __syncthreads(); }
    if (t == 0) outV[b] = red[0] + bc2[0];
}

// ============================================================================
extern "C" void kernel_launch(void* const* d_in, const int* in_sizes, int n_in,
                              void* d_out, int out_size, void* d_ws, size_t ws_size,
                              hipStream_t stream)
{
    const float* x_phys = (const float*)d_in[0];
    const float* x_log  = (const float*)d_in[1];
    const int*   batch  = (const int*)d_in[3];
    const int* intra_s = (const int*)d_in[4];  const int* intra_d = (const int*)d_in[5];
    const int* inter_s = (const int*)d_in[6];  const int* inter_d = (const int*)d_in[7];
    const int* map_s   = (const int*)d_in[8];  const int* map_d   = (const int*)d_in[9];
    const int E_INTRA = in_sizes[4], E_INTER = in_sizes[6], E_MAP = in_sizes[8];
    const int E_ALL = E_INTRA + E_INTER + E_MAP;

    const float* W_phys = (const float*)d_in[14]; const float* b_phys = (const float*)d_in[15];
    const float* W_log  = (const float*)d_in[16]; const float* b_log  = (const float*)d_in[17];
    const float* Wl1 = (const float*)d_in[20]; const float* bl1 = (const float*)d_in[21];
    const float* Wr1 = (const float*)d_in[22];
    const float* Wl2 = (const float*)d_in[23]; const float* bl2 = (const float*)d_in[24];
    const float* Wr2 = (const float*)d_in[25];
    const float* Wg  = (const float*)d_in[26]; const float* bg  = (const float*)d_in[27];
    const float* Wa1 = (const float*)d_in[28]; const float* ba1 = (const float*)d_in[29];
    const float* Wa2 = (const float*)d_in[30]; const float* ba2 = (const float*)d_in[31];
    const float* Wc1 = (const float*)d_in[32]; const float* bc1 = (const float*)d_in[33];
    const float* Wc2 = (const float*)d_in[34]; const float* bc2 = (const float*)d_in[35];

    float* outL = (float*)d_out;
    float* outV = outL + NBAT * AD;

    // ---- carve workspace ----
    char* wsp = (char*)d_ws;
    size_t off = 0;
    auto alloc = [&](size_t sz) -> void* {
        void* p = wsp + off;
        off = (off + sz + 255) & ~(size_t)255;
        return p;
    };
    ushort* hp    = (ushort*)alloc((size_t)NP * 128 * 2);
    ushort* hl    = (ushort*)alloc((size_t)NL * 128 * 2);
    ushort* aggbA = (ushort*)alloc((size_t)NP * 128 * 2);
    ushort* aggbB = (ushort*)alloc((size_t)NP * 128 * 2);
    ushort* Mmap  = (ushort*)alloc((size_t)NP * 128 * 2);

    // counting-sort CSR structures
    const int G1 = (E_ALL + EPB - 1) / EPB;
    const int NSC = NB * G1;
    const int NPARTS = (NSC + 255) / 256;
    int*      cntMat   = (int*)alloc((size_t)NSC * 4);
    int*      partials = (int*)alloc((size_t)NPARTS * 4);
    uint32_t* binned   = (uint32_t*)alloc((size_t)E_ALL * 4);
    int*      rowptr   = (int*)alloc((size_t)(NTOT2 + 1) * 4);
    int*      ss       = (int*)alloc((size_t)E_ALL * 4);

    float*  gate = (float*)alloc((size_t)NP * 4);
    float*  mden = (float*)alloc(2 * NBAT * 4);
    float*  emb  = (float*)alloc(NBAT * 128 * 4);
    ushort* wlt  = (ushort*)alloc((size_t)2 * 4 * 16384 * 2);
    float*  bsum = (float*)alloc(2 * 128 * 4);
    (void)ws_size; (void)out_size; (void)n_in;

    // ---- init: weight prep + encoders + binCount in ONE launch ----
    init_k<<<9 + ENC_B + G1, 256, 0, stream>>>(
        Wl1, Wr1, bl1, Wl2, Wr2, bl2, wlt, bsum,
        x_phys, W_phys, b_phys, x_log, W_log, b_log, hp, hl,
        intra_d, inter_d, map_d, E_INTRA, E_INTER, E_MAP, G1, cntMat);

    // ---- CSR build via LDS counting sort (once; reused both layers) ----
    scanA_k<<<NPARTS, 256, 0, stream>>>(cntMat, partials, NSC);
    scanB_k<<<1, 1024, 0, stream>>>(partials, NPARTS);
    scanC_k<<<NPARTS, 256, 0, stream>>>(cntMat, partials, NSC);
    binPlace_k<<<G1, 256, 0, stream>>>(intra_s, intra_d, inter_s, inter_d, map_s, map_d,
                                       E_INTRA, E_INTER, E_MAP, G1, cntMat, binned);
    csr_k<<<NB, 256, 0, stream>>>(binned, cntMat, G1, E_ALL, rowptr, ss);

    // ---- layer 1: merged gather (intra, inter, map) + GEMM ----
    gather3_k<<<3 * NP / 16, 256, 0, stream>>>(hp, hl, rowptr, ss, aggbA, aggbB, Mmap);
    gemm_k<<<NP / 128, 256, 0, stream>>>(aggbA, aggbB, Mmap, hp,
                                         wlt + 0 * 16384, wlt + 1 * 16384,
                                         wlt + 2 * 16384, wlt + 3 * 16384,
                                         bsum, hp, nullptr, nullptr, nullptr);

    // ---- layer 2: gather (intra, inter; Mmap reused) + GEMM + fused gate ----
    gather2_k<<<2 * NP / 16, 256, 0, stream>>>(hp, rowptr, ss, aggbA, aggbB);
    gemm_k<<<NP / 128, 256, 0, stream>>>(aggbA, aggbB, Mmap, hp,
                                         wlt + 4 * 16384, wlt + 5 * 16384,
                                         wlt + 6 * 16384, wlt + 7 * 16384,
                                         bsum + 128, hp, Wg, bg, gate);

    // ---- attentional pooling + heads ----
    seg_stat_k<<<NBAT, 256, 0, stream>>>(gate, batch, mden, emb);
    wsum_k<<<NP / PNODES, 256, 0, stream>>>(hp, gate, batch, mden, emb);
    heads_k<<<NBAT, 256, 0, stream>>>(emb, Wa1, ba1, Wa2, ba2, Wc1, bc1, Wc2, bc2, outL, outV);
}